// Round 7
// baseline (329.043 us; speedup 1.0000x reference)
//
#include <hip/hip_runtime.h>

#define S_LEN 2048
#define NH 16
#define DIM 128
#define KSZ 32
#define STRD 16
#define SSZ 64
#define NSELB 32
#define NCMP 127
#define TOPN 16
#define WINSZ 512
#define NEGF (-1e30f)
#define NEGTH (-1e29f)
#define SCALE 0.088388347648318447f

typedef __attribute__((ext_vector_type(8))) short bf16x8;
typedef __attribute__((ext_vector_type(4))) float f32x4;

__device__ __forceinline__ unsigned short f2bf(float f) {
  unsigned u = __builtin_bit_cast(unsigned, f);
  return (unsigned short)((u + 0x7FFFu + ((u >> 16) & 1u)) >> 16);
}
__device__ __forceinline__ float bf2f(unsigned short b) {
  return __builtin_bit_cast(float, (unsigned)b << 16);
}
__device__ __forceinline__ bf16x8 pack8(const float* f) {
  bf16x8 r;
#pragma unroll
  for (int i = 0; i < 8; ++i) r[i] = (short)f2bf(f[i]);
  return r;
}

// sub-padded score layout: 4 groups of 32 cols at stride 33 (bank-spread)
#define SCIDX(r, c) ((r) * 132 + (((c) >> 5) * 33) + ((c) & 31))

// ---------- kernel 1: build vtg[h][d][t] and kb[h][t][d], both bf16 ----------
__global__ __launch_bounds__(256) void nsa_build(
    const float* __restrict__ v, const float* __restrict__ k,
    unsigned short* __restrict__ vtg, unsigned short* __restrict__ kb) {
  const int c = blockIdx.x * 256 + threadIdx.x;
  {
    const int h = c >> 15, d = (c >> 8) & 127, tc = c & 255;
    float f[8];
#pragma unroll
    for (int i = 0; i < 8; ++i) f[i] = v[((tc * 8 + i) * NH + h) * DIM + d];
    *(bf16x8*)(vtg + ((h * DIM + d) * S_LEN + tc * 8)) = pack8(f);
  }
  {
    const int h = c >> 15, t = (c >> 4) & 2047, dc = c & 15;
    const float* src = k + ((t * NH + h) * DIM + dc * 8);
    float f[8];
#pragma unroll
    for (int i = 0; i < 8; ++i) f[i] = src[i];
    *(bf16x8*)(kb + ((h * S_LEN + t) * DIM + dc * 8)) = pack8(f);
  }
}

// ---------- kernel 2: compress; cmpk hi/lo bf16, cmpv transposed bf16 ----------
__global__ __launch_bounds__(128) void nsa_compress(
    const float* __restrict__ k, const float* __restrict__ v,
    unsigned short* __restrict__ cmpkh, unsigned short* __restrict__ cmpkl,
    unsigned short* __restrict__ cmpvt) {
  const int c = blockIdx.x & 127;
  const int h = blockIdx.x >> 7;
  const int d = threadIdx.x;
  float sk = 0.f, sv = 0.f;
  if (c < NCMP) {
    const int base = ((c * STRD) * NH + h) * DIM + d;
#pragma unroll
    for (int i = 0; i < KSZ; ++i) {
      sk += k[base + i * NH * DIM];
      sv += v[base + i * NH * DIM];
    }
    sk *= (1.0f / KSZ); sv *= (1.0f / KSZ);
  }
  const unsigned short hi = f2bf(sk);
  const unsigned short lo = f2bf(sk - bf2f(hi));
  cmpkh[(h * 128 + c) * 128 + d] = (c < NCMP) ? hi : 0;
  cmpkl[(h * 128 + c) * 128 + d] = (c < NCMP) ? lo : 0;
  cmpvt[(h * 128 + d) * 128 + c] = (c < NCMP) ? f2bf(sv) : 0;
}

// ---------- shared tile body: QK -> masked online softmax -> PV ----------
template <bool SEL>
__device__ __forceinline__ void run_tile(
    int kt0, int jb, int t0, int l15, int l4,
    const unsigned short* __restrict__ kbh, const unsigned short* __restrict__ vth,
    const bf16x8 (&qfh)[4], char* paw, const unsigned (&maskq)[4],
    float (&mX)[4], float (&lX)[4], f32x4 (&accO)[8]) {
  const unsigned short* kbase = kbh + kt0 * DIM + l4 * 8;
  f32x4 s0 = {0, 0, 0, 0}, s1 = {0, 0, 0, 0};
#pragma unroll
  for (int ks = 0; ks < 4; ++ks) {
    bf16x8 b0 = *(const bf16x8*)(kbase + l15 * DIM + ks * 32);
    bf16x8 b1 = *(const bf16x8*)(kbase + (16 + l15) * DIM + ks * 32);
    s0 = __builtin_amdgcn_mfma_f32_16x16x32_bf16(qfh[ks], b0, s0, 0, 0, 0);
    s1 = __builtin_amdgcn_mfma_f32_16x16x32_bf16(qfh[ks], b1, s1, 0, 0, 0);
  }
  const int c0 = kt0 + l15, c1 = kt0 + 16 + l15;
#pragma unroll
  for (int j = 0; j < 4; ++j) {
    const int qr = l4 * 4 + j;
    const int tq = t0 + qr;
    bool ok0, ok1;
    if (SEL) {
      const bool mb = (maskq[j] >> jb) & 1u;
      ok0 = mb && (c0 <= tq);
      ok1 = mb && (c1 <= tq);
    } else {
      ok0 = (c0 <= tq) && (c0 >= tq - WINSZ);
      ok1 = (c1 <= tq) && (c1 >= tq - WINSZ);
    }
    const float v0 = ok0 ? s0[j] * SCALE : NEGF;
    const float v1 = ok1 ? s1[j] * SCALE : NEGF;
    float rm = fmaxf(v0, v1);
    rm = fmaxf(rm, __shfl_xor(rm, 1));
    rm = fmaxf(rm, __shfl_xor(rm, 2));
    rm = fmaxf(rm, __shfl_xor(rm, 4));
    rm = fmaxf(rm, __shfl_xor(rm, 8));
    if (rm > mX[j]) {
      const float sf = __expf(mX[j] - rm);
      lX[j] *= sf;
#pragma unroll
      for (int n = 0; n < 8; ++n) accO[n][j] *= sf;
      mX[j] = rm;
    }
    const float p0 = (v0 > NEGTH) ? __expf(v0 - mX[j]) : 0.f;
    const float p1 = (v1 > NEGTH) ? __expf(v1 - mX[j]) : 0.f;
    float rs = p0 + p1;
    rs += __shfl_xor(rs, 1);
    rs += __shfl_xor(rs, 2);
    rs += __shfl_xor(rs, 4);
    rs += __shfl_xor(rs, 8);
    lX[j] += rs;
    *(unsigned short*)(paw + qr * 64 + ((l15 * 2) ^ ((qr & 3) << 4))) = f2bf(p0);
    *(unsigned short*)(paw + qr * 64 + (((16 + l15) * 2) ^ ((qr & 3) << 4))) = f2bf(p1);
  }
  bf16x8 ap = *(const bf16x8*)(paw + l15 * 64 + ((l4 * 16) ^ ((l15 & 3) << 4)));
  const unsigned short* vbase = vth + kt0 + l4 * 8;
#pragma unroll
  for (int n = 0; n < 8; ++n) {
    bf16x8 bvv = *(const bf16x8*)(vbase + (n * 16 + l15) * S_LEN);
    accO[n] = __builtin_amdgcn_mfma_f32_16x16x32_bf16(ap, bvv, accO[n], 0, 0, 0);
  }
}

// ---------- kernel 3: main fused NSA ----------
// block = (h, 16 queries), 256 threads = 4 waves, 4 barriers.
// wave0: cmpQK(ct0) | softmax+selection | selected even-halves | merge+out
// wave1: gates+cmpQK(ct1) | cmpPV+scw-init, selected odd-halves | publish
// wave2: cmpQK(ct2) | window even tiles | merge into scw
// wave3: cmpQK(ct3) | window odd tiles  | publish
__global__ __launch_bounds__(256, 2) void nsa_main(
    const float* __restrict__ q, const float* __restrict__ wg,
    const float* __restrict__ bg, const unsigned short* __restrict__ kb,
    const unsigned short* __restrict__ vtg,
    const unsigned short* __restrict__ cmpkh, const unsigned short* __restrict__ cmpkl,
    const unsigned short* __restrict__ cmpvt, float* __restrict__ out) {
  __shared__ float scw[16 * 132];      // cmp scores -> probs -> g0*Ocmp+g2*Owin
  __shared__ float bufA[16 * 132];     // ssel alias (pre-B2) / wave1 sel acc (post-B3)
  __shared__ float bufB[16 * 132];     // wave3 window acc
  __shared__ __align__(16) char pa[4 * 1024];
  __shared__ float gatesLds[48];
  __shared__ unsigned maskLds[16];
  __shared__ float mlA[32], mlB[32];

  const int b = blockIdx.x;
  const int h = ((b & 7) << 1) | ((b >> 3) & 1);   // XCD swizzle
  const int t0 = (b >> 4) << 4;

  const int tid = threadIdx.x;
  const int lane = tid & 63;
  const int w = tid >> 6;
  const int l15 = lane & 15;
  const int l4 = lane >> 4;

  const int nvmax = t0 >> 4;
  const int nct = (nvmax + 31) >> 5;

  const unsigned short* kbh = kb + h * S_LEN * DIM;
  const unsigned short* vth = vtg + h * DIM * S_LEN;

  // ---- Q fragments ----
  bf16x8 qfh[4], qfl[4];
  {
    const float* qp = q + ((t0 + l15) * NH + h) * DIM + l4 * 8;
#pragma unroll
    for (int ks = 0; ks < 4; ++ks) {
      bf16x8 hh, ll;
#pragma unroll
      for (int i = 0; i < 8; ++i) {
        const float x = qp[ks * 32 + i];
        const unsigned short hb = f2bf(x);
        hh[i] = (short)hb;
        ll[i] = (short)f2bf(x - bf2f(hb));
      }
      qfh[ks] = hh; qfl[ks] = ll;
    }
  }

  if (w == 0 && lane < 16) maskLds[lane] = 0u;

  // ---- phase A: cmp QK hi/lo, wave w takes ct=w; wave1 also gates ----
  if (w == 1 && lane < 48) {
    const int qloc = lane / 3, g = lane % 3;
    const float* qr_ = q + ((t0 + qloc) * NH + h) * DIM;
    float acc = bg[g];
#pragma unroll
    for (int d4 = 0; d4 < DIM; d4 += 4) {
      const float4 qv = *(const float4*)(qr_ + d4);
      acc += qv.x * wg[(d4 + 0) * 3 + g] + qv.y * wg[(d4 + 1) * 3 + g] +
             qv.z * wg[(d4 + 2) * 3 + g] + qv.w * wg[(d4 + 3) * 3 + g];
    }
    gatesLds[qloc * 3 + g] = 1.0f / (1.0f + __expf(-acc));
  }
  if (w < nct) {
    const int ct = w;
    const unsigned short* bk = cmpkh + (h * 128 + ct * 32) * 128 + l4 * 8;
    const unsigned short* bkl = cmpkl + (h * 128 + ct * 32) * 128 + l4 * 8;
    f32x4 s0 = {0, 0, 0, 0}, s1 = {0, 0, 0, 0};
#pragma unroll
    for (int ks = 0; ks < 4; ++ks) {
      bf16x8 bh0 = *(const bf16x8*)(bk + l15 * 128 + ks * 32);
      bf16x8 bh1 = *(const bf16x8*)(bk + (16 + l15) * 128 + ks * 32);
      bf16x8 bl0 = *(const bf16x8*)(bkl + l15 * 128 + ks * 32);
      bf16x8 bl1 = *(const bf16x8*)(bkl + (16 + l15) * 128 + ks * 32);
      s0 = __builtin_amdgcn_mfma_f32_16x16x32_bf16(qfh[ks], bh0, s0, 0, 0, 0);
      s0 = __builtin_amdgcn_mfma_f32_16x16x32_bf16(qfl[ks], bh0, s0, 0, 0, 0);
      s0 = __builtin_amdgcn_mfma_f32_16x16x32_bf16(qfh[ks], bl0, s0, 0, 0, 0);
      s1 = __builtin_amdgcn_mfma_f32_16x16x32_bf16(qfh[ks], bh1, s1, 0, 0, 0);
      s1 = __builtin_amdgcn_mfma_f32_16x16x32_bf16(qfl[ks], bh1, s1, 0, 0, 0);
      s1 = __builtin_amdgcn_mfma_f32_16x16x32_bf16(qfh[ks], bl1, s1, 0, 0, 0);
    }
#pragma unroll
    for (int j = 0; j < 4; ++j) {
      const int qr = l4 * 4 + j;
      scw[SCIDX(qr, ct * 32 + l15)] = s0[j] * SCALE;
      scw[SCIDX(qr, ct * 32 + 16 + l15)] = s1[j] * SCALE;
    }
  }

  __syncthreads();   // B1: cmp scores + gates ready

  if (w == 0) {
    // ---- softmax over 127 cmp scores (4 lanes per query) ----
    {
      const int qq = lane >> 2, qg = lane & 3;
      const int tq = t0 + qq;
      const int nv = (tq >= KSZ - 1) ? ((tq - (KSZ - 1)) / STRD + 1) : 0;
      float x[32];
#pragma unroll
      for (int i = 0; i < 32; ++i) x[i] = scw[SCIDX(qq, qg * 32 + i)];
      float m = NEGF;
#pragma unroll
      for (int i = 0; i < 32; ++i)
        if (qg * 32 + i < nv) m = fmaxf(m, x[i]);
      m = fmaxf(m, __shfl_xor(m, 1));
      m = fmaxf(m, __shfl_xor(m, 2));
      float s = 0.f;
#pragma unroll
      for (int i = 0; i < 32; ++i) {
        x[i] = (qg * 32 + i < nv) ? __expf(x[i] - m) : 0.f;
        s += x[i];
      }
      s += __shfl_xor(s, 1);
      s += __shfl_xor(s, 2);
      const float inv = (nv > 0) ? (1.0f / s) : 0.f;
#pragma unroll
      for (int i = 0; i < 32; ++i) scw[SCIDX(qq, qg * 32 + i)] = x[i] * inv;
    }
    // ---- selection scores + top-16 (exact tie semantics) ----
    {
      float* ssel = bufA;
      const int qq = lane >> 2, jg = lane & 3;
      const int tq = t0 + qq;
      float vj[8];
#pragma unroll
      for (int i = 0; i < 8; ++i) {
        const int j = jg * 8 + i;
        const int lo = (4 * j - 1 > 0) ? 4 * j - 1 : 0;
        const int hi = (4 * j + 3 < NCMP - 1) ? 4 * j + 3 : NCMP - 1;
        float ps = 0.f;
        for (int c = lo; c <= hi; ++c) ps += scw[SCIDX(qq, c)];
        float val = (j * SSZ <= tq) ? ps : -1.0f;
        if (j == (tq >> 6)) val += 1e6f;
        vj[i] = val;
        ssel[qq * 33 + j] = val;
      }
      float sv[32];
#pragma unroll
      for (int jp = 0; jp < 32; ++jp) sv[jp] = ssel[qq * 33 + jp];
#pragma unroll
      for (int i = 0; i < 8; ++i) {
        const int j = jg * 8 + i;
        const float my = vj[i];
        int rank = 0;
#pragma unroll
        for (int jp = 0; jp < 32; ++jp)
          rank += (sv[jp] > my) || (sv[jp] == my && jp < j);
        if (rank < TOPN && (j * SSZ <= tq)) atomicOr(&maskLds[qq], 1u << j);
      }
    }
  }

  __syncthreads();   // B2: probs + selection mask ready

  unsigned maskq[4];
#pragma unroll
  for (int j = 0; j < 4; ++j) maskq[j] = maskLds[l4 * 4 + j];
  unsigned unionW = maskq[0] | maskq[1] | maskq[2] | maskq[3];
  unionW |= __shfl_xor(unionW, 16);
  unionW |= __shfl_xor(unionW, 32);

  // wave1: cmp PV first (retire accC into scw before accO goes live)
  if (w == 1) {
    f32x4 accC[8];
#pragma unroll
    for (int n = 0; n < 8; ++n) accC[n] = (f32x4){0, 0, 0, 0};
    for (int ct = 0; ct < nct; ++ct) {
      float f[8];
#pragma unroll
      for (int i = 0; i < 8; ++i) f[i] = scw[SCIDX(l15, ct * 32 + l4 * 8 + i)];
      bf16x8 ap = pack8(f);
      const unsigned short* cvb = cmpvt + (h * 128) * 128 + ct * 32 + l4 * 8;
#pragma unroll
      for (int n = 0; n < 8; ++n) {
        bf16x8 bvv = *(const bf16x8*)(cvb + (n * 16 + l15) * 128);
        accC[n] = __builtin_amdgcn_mfma_f32_16x16x32_bf16(ap, bvv, accC[n], 0, 0, 0);
      }
    }
#pragma unroll
    for (int j = 0; j < 4; ++j) {
      const int qr = l4 * 4 + j;
      const float g0 = gatesLds[qr * 3 + 0];
#pragma unroll
      for (int n = 0; n < 8; ++n) scw[SCIDX(qr, n * 16 + l15)] = g0 * accC[n][j];
    }
  }

  f32x4 accO[8];
#pragma unroll
  for (int n = 0; n < 8; ++n) accO[n] = (f32x4){0, 0, 0, 0};
  float mX[4], lX[4];
#pragma unroll
  for (int j = 0; j < 4; ++j) { mX[j] = NEGF; lX[j] = 0.f; }

  char* paw = pa + w * 1024;

  if (w == 0) {
    for (int jb = 0; jb < NSELB; ++jb) {
      if (!((unionW >> jb) & 1u)) continue;
      run_tile<true>(jb << 6, jb, t0, l15, l4, kbh, vth, qfh, paw, maskq, mX, lX, accO);
    }
  } else if (w == 1) {
    for (int jb = 0; jb < NSELB; ++jb) {
      if (!((unionW >> jb) & 1u)) continue;
      const int kt0 = (jb << 6) + 32;
      if (kt0 > t0 + 15) continue;
      run_tile<true>(kt0, jb, t0, l15, l4, kbh, vth, qfh, paw, maskq, mX, lX, accO);
    }
  } else {
    const int ktlo = (t0 >= WINSZ) ? ((t0 - WINSZ) >> 5) : 0;
    const int ktmax = (t0 + 15) >> 5;
    for (int kt = ktlo + (w - 2); kt <= ktmax; kt += 2)
      run_tile<false>(kt << 5, 0, t0, l15, l4, kbh, vth, qfh, paw, maskq, mX, lX, accO);
  }

  // publish partial states of waves 1 and 3
  if (w == 1 || w == 3) {
    float* buf = (w == 1) ? bufA : bufB;
    float* ml = (w == 1) ? mlA : mlB;
#pragma unroll
    for (int j = 0; j < 4; ++j) {
      const int qr = l4 * 4 + j;
      if (l15 == 0) { ml[qr * 2] = mX[j]; ml[qr * 2 + 1] = lX[j]; }
#pragma unroll
      for (int n = 0; n < 8; ++n) buf[qr * 132 + n * 16 + l15] = accO[n][j];
    }
  }

  __syncthreads();   // B3: partial states + scw init ready

  if (w == 0) {
    // merge selected: (this, bufA) -> g1 * O_sel kept in accO
#pragma unroll
    for (int j = 0; j < 4; ++j) {
      const int qr = l4 * 4 + j;
      const float m1 = mlA[qr * 2], l1 = mlA[qr * 2 + 1];
      const float M = fmaxf(mX[j], m1);
      const float e0 = __expf(mX[j] - M);
      const float e1 = (l1 > 0.f) ? __expf(m1 - M) : 0.f;
      const float gi = gatesLds[qr * 3 + 1] / (lX[j] * e0 + l1 * e1);
#pragma unroll
      for (int n = 0; n < 8; ++n)
        accO[n][j] = gi * (accO[n][j] * e0 + bufA[qr * 132 + n * 16 + l15] * e1);
    }
  } else if (w == 2) {
    // merge window: (this, bufB) -> scw += g2 * O_win
#pragma unroll
    for (int j = 0; j < 4; ++j) {
      const int qr = l4 * 4 + j;
      const float m1 = mlB[qr * 2], l1 = mlB[qr * 2 + 1];
      const float M = fmaxf(mX[j], m1);
      const float e0 = __expf(mX[j] - M);
      const float e1 = (l1 > 0.f) ? __expf(m1 - M) : 0.f;
      const float gi = gatesLds[qr * 3 + 2] / (lX[j] * e0 + l1 * e1);
#pragma unroll
      for (int n = 0; n < 8; ++n)
        scw[SCIDX(qr, n * 16 + l15)] +=
            gi * (accO[n][j] * e0 + bufB[qr * 132 + n * 16 + l15] * e1);
    }
  }

  __syncthreads();   // B4: scw holds g0*Ocmp + g2*Owin

  if (w == 0) {
#pragma unroll
    for (int j = 0; j < 4; ++j) {
      const int qr = l4 * 4 + j;
      const int tq = t0 + qr;
#pragma unroll
      for (int n = 0; n < 8; ++n)
        out[(tq * NH + h) * DIM + n * 16 + l15] =
            scw[SCIDX(qr, n * 16 + l15)] + accO[n][j];
    }
  }
}

extern "C" void kernel_launch(void* const* d_in, const int* in_sizes, int n_in,
                              void* d_out, int out_size, void* d_ws, size_t ws_size,
                              hipStream_t stream) {
  const float* q  = (const float*)d_in[0];
  const float* k  = (const float*)d_in[1];
  const float* v  = (const float*)d_in[2];
  const float* wg = (const float*)d_in[3];
  const float* bg = (const float*)d_in[4];
  float* out = (float*)d_out;

  unsigned short* vtg   = (unsigned short*)d_ws;            // 8 MB
  unsigned short* kb    = vtg + NH * DIM * S_LEN;           // 8 MB
  unsigned short* cmpkh = kb + NH * S_LEN * DIM;            // 512 KB
  unsigned short* cmpkl = cmpkh + NH * 128 * 128;           // 512 KB
  unsigned short* cmpvt = cmpkl + NH * 128 * 128;           // 512 KB

  nsa_build<<<2048, 256, 0, stream>>>(v, k, vtg, kb);
  nsa_compress<<<NH * 128, 128, 0, stream>>>(k, v, cmpkh, cmpkl, cmpvt);
  nsa_main<<<2048, 256, 0, stream>>>(q, wg, bg, kb, vtg, cmpkh, cmpkl, cmpvt, out);
}